// Round 1
// baseline (3121.672 us; speedup 1.0000x reference)
//
#include <hip/hip_runtime.h>

// Problem constants
#define B_ 2
#define S_ 2048
#define H_ 2048
#define NH_ 16
#define NKV_ 8
#define HD_ 128
#define GROUPS_ (NH_ / NKV_)
#define EPS_ 1e-6f
#define SCALE_ 0.08838834764831845f   // 1/sqrt(128)

// GEMM tiling: 64x64 block tile, 16-wide K tile, 256 threads, 4x4 per thread.
#define BM 64
#define BK 16

// ---------------------------------------------------------------------------
// C[m][n] = alpha * sum_k A[m][k] * B[n][k]   (A: MxK row-major, B: NxK row-major)
// Grid: (N/64, M/64 [, z handled by caller]); block: 256.
// ---------------------------------------------------------------------------
__device__ __forceinline__ void gemm_abt_body(
    const float* __restrict__ A, const float* __restrict__ Bm, float* __restrict__ C,
    int K, int lda, int ldb, int ldc, float alpha)
{
    __shared__ __align__(16) float As[BK][BM];   // As[k][m]
    __shared__ __align__(16) float Bs[BK][BM];   // Bs[k][n]
    const int tid = threadIdx.x;
    const int tx = tid & 15, ty = tid >> 4;
    const int m0 = blockIdx.y * BM, n0 = blockIdx.x * BM;

    // load indices: each thread loads a float4 from one row of A and one row of B
    const int lm = tid >> 2;          // 0..63 : row within tile
    const int lk = (tid & 3) * 4;     // 0,4,8,12 : k offset
    const float* Ap = A + (size_t)(m0 + lm) * lda + lk;
    const float* Bp = Bm + (size_t)(n0 + lm) * ldb + lk;

    float acc[4][4] = {};

    for (int k0 = 0; k0 < K; k0 += BK) {
        float4 fa = *(const float4*)(Ap + k0);
        float4 fb = *(const float4*)(Bp + k0);
        As[lk + 0][lm] = fa.x; As[lk + 1][lm] = fa.y;
        As[lk + 2][lm] = fa.z; As[lk + 3][lm] = fa.w;
        Bs[lk + 0][lm] = fb.x; Bs[lk + 1][lm] = fb.y;
        Bs[lk + 2][lm] = fb.z; Bs[lk + 3][lm] = fb.w;
        __syncthreads();
#pragma unroll
        for (int kk = 0; kk < BK; ++kk) {
            float a[4], b[4];
#pragma unroll
            for (int i = 0; i < 4; i++) a[i] = As[kk][ty * 4 + i];
#pragma unroll
            for (int j = 0; j < 4; j++) b[j] = Bs[kk][tx * 4 + j];
#pragma unroll
            for (int i = 0; i < 4; i++)
#pragma unroll
                for (int j = 0; j < 4; j++)
                    acc[i][j] = fmaf(a[i], b[j], acc[i][j]);
        }
        __syncthreads();
    }

#pragma unroll
    for (int i = 0; i < 4; i++) {
        float* crow = C + (size_t)(m0 + ty * 4 + i) * ldc + n0 + tx * 4;
#pragma unroll
        for (int j = 0; j < 4; j++) crow[j] = alpha * acc[i][j];
    }
}

// ---------------------------------------------------------------------------
// C[m][n] = sum_k A[m][k] * B[k][n]   (A: MxK row-major, B: KxN row-major)
// ---------------------------------------------------------------------------
__device__ __forceinline__ void gemm_ab_body(
    const float* __restrict__ A, const float* __restrict__ Bm, float* __restrict__ C,
    int K, int lda, int ldb, int ldc)
{
    __shared__ __align__(16) float As[BK][BM];
    __shared__ __align__(16) float Bs[BK][BM];
    const int tid = threadIdx.x;
    const int tx = tid & 15, ty = tid >> 4;
    const int m0 = blockIdx.y * BM, n0 = blockIdx.x * BM;

    const int lm = tid >> 2;
    const int lk = (tid & 3) * 4;
    const int bk = tid >> 4;          // 0..15 : k row of B tile
    const int bn = (tid & 15) * 4;    // 0..60 : n offset
    const float* Ap = A + (size_t)(m0 + lm) * lda + lk;
    const float* Bp = Bm + (size_t)bk * ldb + n0 + bn;

    float acc[4][4] = {};

    for (int k0 = 0; k0 < K; k0 += BK) {
        float4 fa = *(const float4*)(Ap + k0);
        float4 fb = *(const float4*)(Bp + (size_t)k0 * ldb);
        As[lk + 0][lm] = fa.x; As[lk + 1][lm] = fa.y;
        As[lk + 2][lm] = fa.z; As[lk + 3][lm] = fa.w;
        *(float4*)&Bs[bk][bn] = fb;
        __syncthreads();
#pragma unroll
        for (int kk = 0; kk < BK; ++kk) {
            float a[4], b[4];
#pragma unroll
            for (int i = 0; i < 4; i++) a[i] = As[kk][ty * 4 + i];
#pragma unroll
            for (int j = 0; j < 4; j++) b[j] = Bs[kk][tx * 4 + j];
#pragma unroll
            for (int i = 0; i < 4; i++)
#pragma unroll
                for (int j = 0; j < 4; j++)
                    acc[i][j] = fmaf(a[i], b[j], acc[i][j]);
        }
        __syncthreads();
    }

#pragma unroll
    for (int i = 0; i < 4; i++) {
        float* crow = C + (size_t)(m0 + ty * 4 + i) * ldc + n0 + tx * 4;
#pragma unroll
        for (int j = 0; j < 4; j++) crow[j] = acc[i][j];
    }
}

// ---------------------------------------------------------------------------
__global__ __launch_bounds__(256) void gemm_abt_kernel(
    const float* __restrict__ A, const float* __restrict__ Bm, float* __restrict__ C,
    int K, int lda, int ldb, int ldc, float alpha)
{
    gemm_abt_body(A, Bm, C, K, lda, ldb, ldc, alpha);
}

// scores[z] = SCALE * Q_h @ K_h^T ; z = b*NH + h
__global__ __launch_bounds__(256) void scores_kernel(
    const float* __restrict__ qb, const float* __restrict__ kb, float* __restrict__ attnw)
{
    const int z = blockIdx.z;
    const int b = z / NH_, h = z % NH_;
    const float* A = qb + (size_t)z * S_ * HD_;
    const float* Bm = kb + (size_t)(b * NKV_ + h / GROUPS_) * S_ * HD_;
    float* C = attnw + (size_t)z * S_ * S_;
    gemm_abt_body(A, Bm, C, HD_, HD_, HD_, S_, SCALE_);
}

// attn_out[b, q, h*HD + d] = sum_k W[b,h,q,k] * V[b,kvh,k,d]
__global__ __launch_bounds__(256) void pv_kernel(
    const float* __restrict__ attnw, const float* __restrict__ vb, float* __restrict__ ao)
{
    const int z = blockIdx.z;
    const int b = z / NH_, h = z % NH_;
    const float* A = attnw + (size_t)z * S_ * S_;
    const float* Bm = vb + (size_t)(b * NKV_ + h / GROUPS_) * S_ * HD_;
    float* C = ao + (size_t)b * S_ * (NH_ * HD_) + h * HD_;
    gemm_ab_body(A, Bm, C, S_, S_, HD_, NH_ * HD_);
}

// ---------------------------------------------------------------------------
// Per-head RMSNorm + RoPE + transpose (b,s,h,d) -> (b,h,s,d).
// One block of 128 threads per (b,s,h).
// ---------------------------------------------------------------------------
__global__ __launch_bounds__(128) void norm_rope_kernel(
    const float* __restrict__ raw, const float* __restrict__ w,
    const float* __restrict__ cosb, const float* __restrict__ sinb,
    float* __restrict__ outb, int nheads)
{
    __shared__ float s_xn[HD_];
    __shared__ float s_red[2];
    const int idx = blockIdx.x;
    const int h = idx % nheads;
    const int s = (idx / nheads) % S_;
    const int b = idx / (nheads * S_);
    const int d = threadIdx.x;

    const float x = raw[((size_t)(b * S_ + s) * nheads + h) * HD_ + d];
    float ss = x * x;
#pragma unroll
    for (int off = 1; off < 64; off <<= 1) ss += __shfl_xor(ss, off);
    if ((d & 63) == 0) s_red[d >> 6] = ss;
    __syncthreads();
    const float tot = s_red[0] + s_red[1];
    const float r = rsqrtf(tot * (1.0f / HD_) + EPS_);
    const float xn = x * r * w[d];
    s_xn[d] = xn;
    __syncthreads();
    const float other = (d < 64) ? s_xn[d + 64] : s_xn[d - 64];
    const size_t cbase = (size_t)(b * S_ + s) * HD_;
    const float c = cosb[cbase + d];
    const float sn = sinb[cbase + d];
    const float res = (d < 64) ? (xn * c - other * sn) : (xn * c + other * sn);
    outb[((size_t)(b * nheads + h) * S_ + s) * HD_ + d] = res;
}

// V transpose (b,s,h,d) -> (b,h,s,d)
__global__ __launch_bounds__(128) void vtrans_kernel(
    const float* __restrict__ vraw, float* __restrict__ vb)
{
    const int idx = blockIdx.x;
    const int h = idx % NKV_;
    const int s = (idx / NKV_) % S_;
    const int b = idx / (NKV_ * S_);
    const int d = threadIdx.x;
    vb[((size_t)(b * NKV_ + h) * S_ + s) * HD_ + d] =
        vraw[((size_t)(b * S_ + s) * NKV_ + h) * HD_ + d];
}

// ---------------------------------------------------------------------------
// Row softmax, in place. One block (256 threads) per row of 2048.
// ---------------------------------------------------------------------------
__global__ __launch_bounds__(256) void softmax_kernel(float* __restrict__ wgt)
{
    float* p = wgt + (size_t)blockIdx.x * S_;
    const int t = threadIdx.x;
    float v[8];
    float mx = -3.4e38f;
#pragma unroll
    for (int i = 0; i < 8; i++) { v[i] = p[t + i * 256]; mx = fmaxf(mx, v[i]); }
#pragma unroll
    for (int off = 1; off < 64; off <<= 1) mx = fmaxf(mx, __shfl_xor(mx, off));
    __shared__ float redm[4];
    __shared__ float reds[4];
    const int wave = t >> 6;
    if ((t & 63) == 0) redm[wave] = mx;
    __syncthreads();
    mx = fmaxf(fmaxf(redm[0], redm[1]), fmaxf(redm[2], redm[3]));
    float sum = 0.f;
#pragma unroll
    for (int i = 0; i < 8; i++) { v[i] = expf(v[i] - mx); sum += v[i]; }
#pragma unroll
    for (int off = 1; off < 64; off <<= 1) sum += __shfl_xor(sum, off);
    if ((t & 63) == 0) reds[wave] = sum;
    __syncthreads();
    sum = reds[0] + reds[1] + reds[2] + reds[3];
    const float inv = 1.0f / sum;
#pragma unroll
    for (int i = 0; i < 8; i++) p[t + i * 256] = v[i] * inv;
}

// ---------------------------------------------------------------------------
extern "C" void kernel_launch(void* const* d_in, const int* in_sizes, int n_in,
                              void* d_out, int out_size, void* d_ws, size_t ws_size,
                              hipStream_t stream)
{
    const float* hs   = (const float*)d_in[0];
    const float* mm   = (const float*)d_in[1];
    const float* cosb = (const float*)d_in[2];
    const float* sinb = (const float*)d_in[3];
    // d_in[4] = attention_mask, all-true in this problem -> add_mask == 0
    const float* Wq = (const float*)d_in[5];
    const float* Wk = (const float*)d_in[6];
    const float* Wv = (const float*)d_in[7];
    const float* Wo = (const float*)d_in[8];
    const float* qw = (const float*)d_in[9];
    const float* kw = (const float*)d_in[10];

    float* out   = (float*)d_out;                    // (B,S,H)
    float* attnw = out + (size_t)B_ * S_ * H_;       // (B,NH,S,S)

    // Stage raw QKV projections inside the attn_weights region (dead until scores).
    float* qraw = attnw;                                   // B*S*NH*HD  = 8.4M
    float* kraw = qraw + (size_t)B_ * S_ * NH_ * HD_;      // B*S*NKV*HD = 4.2M
    float* vraw = kraw + (size_t)B_ * S_ * NKV_ * HD_;     // 4.2M

    // Workspace: rope'd Q/K/V in (b,h,s,d) layout. attn_out aliases dead qb.
    float* qb = (float*)d_ws;                              // B*NH*S*HD
    float* kb = qb + (size_t)B_ * NH_ * S_ * HD_;          // B*NKV*S*HD
    float* vb = kb + (size_t)B_ * NKV_ * S_ * HD_;         // B*NKV*S*HD
    float* ao = qb;  // reuse after scores consume qb

    // 1) QKV projections (A @ W^T)
    gemm_abt_kernel<<<dim3(H_ / BM, (B_ * S_) / BM), 256, 0, stream>>>(
        hs, Wq, qraw, H_, H_, H_, NH_ * HD_, 1.0f);
    gemm_abt_kernel<<<dim3((NKV_ * HD_) / BM, (B_ * S_) / BM), 256, 0, stream>>>(
        mm, Wk, kraw, H_, H_, H_, NKV_ * HD_, 1.0f);
    gemm_abt_kernel<<<dim3((NKV_ * HD_) / BM, (B_ * S_) / BM), 256, 0, stream>>>(
        mm, Wv, vraw, H_, H_, H_, NKV_ * HD_, 1.0f);

    // 2) RMSNorm + RoPE (+ transpose) for Q and K; transpose V
    norm_rope_kernel<<<B_ * S_ * NH_, 128, 0, stream>>>(qraw, qw, cosb, sinb, qb, NH_);
    norm_rope_kernel<<<B_ * S_ * NKV_, 128, 0, stream>>>(kraw, kw, cosb, sinb, kb, NKV_);
    vtrans_kernel<<<B_ * S_ * NKV_, 128, 0, stream>>>(vraw, vb);

    // 3) scores = SCALE * Q K^T   (overwrites the staging region too)
    scores_kernel<<<dim3(S_ / BM, S_ / BM, B_ * NH_), 256, 0, stream>>>(qb, kb, attnw);

    // 4) softmax rows -> final attn_weights output
    softmax_kernel<<<B_ * NH_ * S_, 256, 0, stream>>>(attnw);

    // 5) attn_out = W @ V   (written as (B,S,NH*HD))
    pv_kernel<<<dim3(HD_ / BM, S_ / BM, B_ * NH_), 256, 0, stream>>>(attnw, vb, ao);

    // 6) out = attn_out @ Wo^T
    gemm_abt_kernel<<<dim3(H_ / BM, (B_ * S_) / BM), 256, 0, stream>>>(
        ao, Wo, out, NH_ * HD_, NH_ * HD_, H_, H_, 1.0f);
}